// Round 2
// baseline (1322.532 us; speedup 1.0000x reference)
//
#include <hip/hip_runtime.h>
#include <stdint.h>

#define N_NODES 50000
#define N_EDGES 800000
#define DMODEL  256
#define FEDGE   64
#define N_ETILES (N_EDGES / 16)

typedef short short8 __attribute__((ext_vector_type(8)));
typedef float floatx4 __attribute__((ext_vector_type(4)));
typedef unsigned short ushort_t;

__device__ __forceinline__ ushort_t f2bf(float f) {
  union { float f; unsigned int i; } v; v.f = f;
  unsigned int x = v.i;
  unsigned int r = x + 0x7fffu + ((x >> 16) & 1u);  // RNE
  return (ushort_t)(r >> 16);
}
__device__ __forceinline__ short8 ldg16(const ushort_t* p) {
  return *(const short8*)(const void*)p;
}

// ---------------------------------------------------------------------------
// prep: M = bf16(W_le @ W_e2), c = W_le @ b_e2 (f32); also bf16 copies of
// W_e1 / W_g1 / W_g2 so all MFMA B-operands are 16B bf16 loads.
// Fusion valid because polarity gating is a per-edge SCALAR:
//   edge_emb = p' * (t1 @ M^T + c) + b_le,  p' = clip(pol,0,1)+0.01
// ---------------------------------------------------------------------------
__global__ void prep_kernel(const float* __restrict__ W_le,
                            const float* __restrict__ W_e2,
                            const float* __restrict__ b_e2,
                            const float* __restrict__ W_e1,
                            const float* __restrict__ W_g1,
                            const float* __restrict__ W_g2,
                            ushort_t* __restrict__ Mw, float* __restrict__ cw,
                            ushort_t* __restrict__ We1bf,
                            ushort_t* __restrict__ Wg1bf,
                            ushort_t* __restrict__ Wg2bf) {
  int d = blockIdx.x, k = threadIdx.x;
  float acc = 0.f;
  for (int j = 0; j < DMODEL; ++j)
    acc += W_le[d * DMODEL + j] * W_e2[j * DMODEL + k];
  Mw[d * DMODEL + k] = f2bf(acc);
  Wg1bf[d * DMODEL + k] = f2bf(W_g1[d * DMODEL + k]);
  Wg2bf[d * DMODEL + k] = f2bf(W_g2[d * DMODEL + k]);
  if (k < FEDGE) We1bf[d * FEDGE + k] = f2bf(W_e1[d * FEDGE + k]);
  if (k == 0) {
    float cc = 0.f;
    for (int j = 0; j < DMODEL; ++j) cc += W_le[d * DMODEL + j] * b_e2[j];
    cw[d] = cc;
  }
}

// ---------------------------------------------------------------------------
// edge kernel: persistent workgroups; B fragments (W_e1, M) live in registers
// for the whole kernel. Per 16-edge tile:
//   t1 = relu(raw @ W_e1^T + b_e1)            [K=64,  2 MFMA k-steps]
//   pre = t1 @ M^T                            [K=256, 8 MFMA k-steps]
//   msg = relu(x[src] + p'*(pre+c) + b_le); atomicAdd into aggr[dst]
// MFMA 16x16x32 bf16. C/D layout: col=lane&15, row=(lane>>4)*4+reg.
// ---------------------------------------------------------------------------
__global__ __launch_bounds__(256, 2)
void edge_kernel(const float* __restrict__ x,
                 const int* __restrict__ eidx,
                 const float* __restrict__ eattr,
                 const ushort_t* __restrict__ We1bf,
                 const float* __restrict__ b_e1,
                 const float* __restrict__ b_le,
                 const ushort_t* __restrict__ Mw,
                 const float* __restrict__ cw,
                 float* __restrict__ aggr) {
  __shared__ __align__(16) ushort_t raw_lds[16 * 72];    // 16 edges x 64 feats, +pad
  __shared__ __align__(16) ushort_t t1_lds[16 * 264];    // 16 x 256, +pad
  __shared__ float pp_lds[16];
  __shared__ int src_lds[16];
  __shared__ int dst_lds[16];

  const int tid  = threadIdx.x;
  const int lane = tid & 63;
  const int wave = tid >> 6;
  const int l16  = lane & 15;
  const int quad = lane >> 4;

  // persistent B fragments: lane n=l16 holds 8 consecutive k of W[n][k] (=B^T row)
  short8 bM[4][8];
  short8 b1[4][2];
  float be1v[4], cv[4], blv[4];
  int ncol[4];
#pragma unroll
  for (int nt = 0; nt < 4; ++nt) {
    int n = wave * 64 + nt * 16 + l16;
    ncol[nt] = n;
#pragma unroll
    for (int k = 0; k < 2; ++k)
      b1[nt][k] = ldg16(We1bf + n * FEDGE + k * 32 + quad * 8);
#pragma unroll
    for (int k = 0; k < 8; ++k)
      bM[nt][k] = ldg16(Mw + n * DMODEL + k * 32 + quad * 8);
    be1v[nt] = b_e1[n];
    cv[nt]   = cw[n];
    blv[nt]  = b_le[n];
  }

  const int stage_r = tid >> 4;
  const int stage_c = (tid & 15) * 4;

  for (int tile = blockIdx.x; tile < N_ETILES; tile += gridDim.x) {
    const long ebase = (long)tile * 16;
    __syncthreads();  // previous-iteration readers of raw/pp/src/dst/t1 done

    // stage raw tile (edge_attr cols 1..64) as bf16, polarity, indices
    {
      const float* p = eattr + (ebase + stage_r) * 65 + 1 + stage_c;
      ushort_t* q = raw_lds + stage_r * 72 + stage_c;
      q[0] = f2bf(p[0]); q[1] = f2bf(p[1]); q[2] = f2bf(p[2]); q[3] = f2bf(p[3]);
      if (tid < 16) {
        float pol = eattr[(ebase + tid) * 65];
        pol = fminf(fmaxf(pol, 0.f), 1.f) + 0.01f;
        pp_lds[tid] = pol;
        src_lds[tid] = eidx[ebase + tid];
        dst_lds[tid] = eidx[N_EDGES + ebase + tid];
      }
    }
    __syncthreads();

    // GEMM1: t1 = relu(raw @ W_e1^T + b_e1)
    floatx4 acc[4];
#pragma unroll
    for (int nt = 0; nt < 4; ++nt) acc[nt] = (floatx4){0.f, 0.f, 0.f, 0.f};
#pragma unroll
    for (int k = 0; k < 2; ++k) {
      short8 a = *(const short8*)(const void*)(raw_lds + l16 * 72 + k * 32 + quad * 8);
#pragma unroll
      for (int nt = 0; nt < 4; ++nt)
        acc[nt] = __builtin_amdgcn_mfma_f32_16x16x32_bf16(a, b1[nt][k], acc[nt], 0, 0, 0);
    }
#pragma unroll
    for (int nt = 0; nt < 4; ++nt) {
#pragma unroll
      for (int r = 0; r < 4; ++r) {
        int row = quad * 4 + r;
        t1_lds[row * 264 + ncol[nt]] = f2bf(fmaxf(acc[nt][r] + be1v[nt], 0.f));
      }
    }
    __syncthreads();

    // GEMM2: pre = t1 @ M^T
#pragma unroll
    for (int nt = 0; nt < 4; ++nt) acc[nt] = (floatx4){0.f, 0.f, 0.f, 0.f};
#pragma unroll
    for (int k = 0; k < 8; ++k) {
      short8 a = *(const short8*)(const void*)(t1_lds + l16 * 264 + k * 32 + quad * 8);
#pragma unroll
      for (int nt = 0; nt < 4; ++nt)
        acc[nt] = __builtin_amdgcn_mfma_f32_16x16x32_bf16(a, bM[nt][k], acc[nt], 0, 0, 0);
    }

    // epilogue: msg = relu(x[src] + p'*(pre+c) + b_le) -> atomic scatter-add
#pragma unroll
    for (int nt = 0; nt < 4; ++nt) {
#pragma unroll
      for (int r = 0; r < 4; ++r) {
        int row = quad * 4 + r;
        float emb = pp_lds[row] * (acc[nt][r] + cv[nt]) + blv[nt];
        float xv  = x[(long)src_lds[row] * DMODEL + ncol[nt]];
        float msg = fmaxf(xv + emb, 0.f);
        atomicAdd(aggr + (long)dst_lds[row] * DMODEL + ncol[nt], msg);
      }
    }
  }
}

// ---------------------------------------------------------------------------
// node kernel: h = (x+aggr) @ W_g1^T + b_g1 ; LayerNorm ; relu ; @ W_g2^T + b_g2
// one workgroup per 16 nodes
// ---------------------------------------------------------------------------
__global__ __launch_bounds__(256)
void node_kernel(const float* __restrict__ x,
                 const float* __restrict__ aggr,
                 const ushort_t* __restrict__ Wg1bf,
                 const float* __restrict__ b_g1,
                 const float* __restrict__ ln_g,
                 const float* __restrict__ ln_b,
                 const ushort_t* __restrict__ Wg2bf,
                 const float* __restrict__ b_g2,
                 float* __restrict__ out) {
  __shared__ __align__(16) ushort_t a_lds[16 * 264];
  __shared__ __align__(16) float h_lds[16 * 264];
  __shared__ float mu_lds[16], rs_lds[16];

  const int tid  = threadIdx.x;
  const int lane = tid & 63;
  const int wave = tid >> 6;
  const int l16  = lane & 15;
  const int quad = lane >> 4;
  const long nbase = (long)blockIdx.x * 16;

  // stage in = bf16(x + aggr)
  {
    int r = tid >> 4, cb = (tid & 15) * 16;
    const float* xp = x + (nbase + r) * DMODEL + cb;
    const float* ap = aggr + (nbase + r) * DMODEL + cb;
#pragma unroll
    for (int i = 0; i < 16; ++i)
      a_lds[r * 264 + cb + i] = f2bf(xp[i] + ap[i]);
  }
  __syncthreads();

  floatx4 acc[4];
  int ncol[4];
#pragma unroll
  for (int nt = 0; nt < 4; ++nt) { ncol[nt] = wave * 64 + nt * 16 + l16; acc[nt] = (floatx4){0.f,0.f,0.f,0.f}; }
#pragma unroll
  for (int k = 0; k < 8; ++k) {
    short8 a = *(const short8*)(const void*)(a_lds + l16 * 264 + k * 32 + quad * 8);
#pragma unroll
    for (int nt = 0; nt < 4; ++nt) {
      short8 b = ldg16(Wg1bf + ncol[nt] * DMODEL + k * 32 + quad * 8);
      acc[nt] = __builtin_amdgcn_mfma_f32_16x16x32_bf16(a, b, acc[nt], 0, 0, 0);
    }
  }
#pragma unroll
  for (int nt = 0; nt < 4; ++nt) {
    float bg = b_g1[ncol[nt]];
#pragma unroll
    for (int r = 0; r < 4; ++r)
      h_lds[(quad * 4 + r) * 264 + ncol[nt]] = acc[nt][r] + bg;
  }
  __syncthreads();

  // LayerNorm stats: 16 lanes per row, shfl-xor reduce within width 16
  {
    int r = tid >> 4, p = tid & 15;
    float s = 0.f, ss = 0.f;
#pragma unroll
    for (int i = 0; i < 16; ++i) { float v = h_lds[r * 264 + p + 16 * i]; s += v; ss += v * v; }
#pragma unroll
    for (int o = 8; o >= 1; o >>= 1) { s += __shfl_xor(s, o, 16); ss += __shfl_xor(ss, o, 16); }
    if (p == 0) {
      float mu = s * (1.f / 256.f);
      float var = ss * (1.f / 256.f) - mu * mu;
      mu_lds[r] = mu; rs_lds[r] = rsqrtf(var + 1e-5f);
    }
  }
  __syncthreads();
  {
    int r = tid >> 4, cb = (tid & 15) * 16;
    float mu = mu_lds[r], rs = rs_lds[r];
#pragma unroll
    for (int i = 0; i < 16; ++i) {
      int c = cb + i;
      float hn = (h_lds[r * 264 + c] - mu) * rs * ln_g[c] + ln_b[c];
      a_lds[r * 264 + c] = f2bf(fmaxf(hn, 0.f));
    }
  }
  __syncthreads();

  // GEMM2 -> out
#pragma unroll
  for (int nt = 0; nt < 4; ++nt) acc[nt] = (floatx4){0.f, 0.f, 0.f, 0.f};
#pragma unroll
  for (int k = 0; k < 8; ++k) {
    short8 a = *(const short8*)(const void*)(a_lds + l16 * 264 + k * 32 + quad * 8);
#pragma unroll
    for (int nt = 0; nt < 4; ++nt) {
      short8 b = ldg16(Wg2bf + ncol[nt] * DMODEL + k * 32 + quad * 8);
      acc[nt] = __builtin_amdgcn_mfma_f32_16x16x32_bf16(a, b, acc[nt], 0, 0, 0);
    }
  }
#pragma unroll
  for (int nt = 0; nt < 4; ++nt) {
    float bg = b_g2[ncol[nt]];
#pragma unroll
    for (int r = 0; r < 4; ++r)
      out[(nbase + quad * 4 + r) * DMODEL + ncol[nt]] = acc[nt][r] + bg;
  }
}

// ---------------------------------------------------------------------------
extern "C" void kernel_launch(void* const* d_in, const int* in_sizes, int n_in,
                              void* d_out, int out_size, void* d_ws, size_t ws_size,
                              hipStream_t stream) {
  const float* x     = (const float*)d_in[0];
  const int*   eidx  = (const int*)d_in[1];
  const float* eattr = (const float*)d_in[2];
  const float* W_e1  = (const float*)d_in[3];
  const float* b_e1  = (const float*)d_in[4];
  const float* W_e2  = (const float*)d_in[5];
  const float* b_e2  = (const float*)d_in[6];
  const float* W_le  = (const float*)d_in[7];
  const float* b_le  = (const float*)d_in[8];
  const float* W_g1  = (const float*)d_in[9];
  const float* b_g1  = (const float*)d_in[10];
  const float* ln_g  = (const float*)d_in[11];
  const float* ln_b  = (const float*)d_in[12];
  const float* W_g2  = (const float*)d_in[13];
  const float* b_g2  = (const float*)d_in[14];
  float* out = (float*)d_out;

  char* ws = (char*)d_ws;
  ushort_t* Mw    = (ushort_t*)(ws);            // 131072 B
  ushort_t* Wg1bf = (ushort_t*)(ws + 131072);   // 131072 B
  ushort_t* Wg2bf = (ushort_t*)(ws + 262144);   // 131072 B
  ushort_t* We1bf = (ushort_t*)(ws + 393216);   // 32768 B
  float*    cw    = (float*)   (ws + 425984);   // 1024 B
  float*    aggr  = (float*)   (ws + 427008);   // 51.2 MB

  hipMemsetAsync(aggr, 0, (size_t)N_NODES * DMODEL * sizeof(float), stream);
  prep_kernel<<<dim3(DMODEL), dim3(DMODEL), 0, stream>>>(
      W_le, W_e2, b_e2, W_e1, W_g1, W_g2, Mw, cw, We1bf, Wg1bf, Wg2bf);
  edge_kernel<<<dim3(2048), dim3(256), 0, stream>>>(
      x, eidx, eattr, We1bf, b_e1, b_le, Mw, cw, aggr);
  node_kernel<<<dim3(N_NODES / 16), dim3(256), 0, stream>>>(
      x, aggr, Wg1bf, b_g1, ln_g, ln_b, Wg2bf, b_g2, out);
}

// Round 3
// 1224.939 us; speedup vs baseline: 1.0797x; 1.0797x over previous
//
#include <hip/hip_runtime.h>
#include <stdint.h>

#define N_NODES 50000
#define N_EDGES 800000
#define DMODEL  256
#define FEDGE   64
#define TILE_E  64
#define N_ETILES (N_EDGES / TILE_E)   // 12500
#define TILE_N  64
#define N_NTILES ((N_NODES + TILE_N - 1) / TILE_N)  // 782

typedef short short8 __attribute__((ext_vector_type(8)));
typedef float floatx4 __attribute__((ext_vector_type(4)));
typedef unsigned short ushort_t;

__device__ __forceinline__ ushort_t f2bf(float f) {
  union { float f; unsigned int i; } v; v.f = f;
  unsigned int x = v.i;
  unsigned int r = x + 0x7fffu + ((x >> 16) & 1u);  // RNE
  return (ushort_t)(r >> 16);
}
__device__ __forceinline__ short8 ldg16(const ushort_t* p) {
  return *(const short8*)(const void*)p;
}

// ---------------------------------------------------------------------------
// prep: M = bf16(W_le @ W_e2), c = W_le @ b_e2 (f32); bf16 copies of
// W_e1 / W_g1 / W_g2. Fusion valid since polarity gate is a per-edge scalar:
//   edge_emb = p' * (t1 @ M^T + c) + b_le,  p' = clip(pol,0,1)+0.01
// ---------------------------------------------------------------------------
__global__ void prep_kernel(const float* __restrict__ W_le,
                            const float* __restrict__ W_e2,
                            const float* __restrict__ b_e2,
                            const float* __restrict__ W_e1,
                            const float* __restrict__ W_g1,
                            const float* __restrict__ W_g2,
                            ushort_t* __restrict__ Mw, float* __restrict__ cw,
                            ushort_t* __restrict__ We1bf,
                            ushort_t* __restrict__ Wg1bf,
                            ushort_t* __restrict__ Wg2bf) {
  int d = blockIdx.x, k = threadIdx.x;
  float acc = 0.f;
  for (int j = 0; j < DMODEL; ++j)
    acc += W_le[d * DMODEL + j] * W_e2[j * DMODEL + k];
  Mw[d * DMODEL + k] = f2bf(acc);
  Wg1bf[d * DMODEL + k] = f2bf(W_g1[d * DMODEL + k]);
  Wg2bf[d * DMODEL + k] = f2bf(W_g2[d * DMODEL + k]);
  if (k < FEDGE) We1bf[d * FEDGE + k] = f2bf(W_e1[d * FEDGE + k]);
  if (k == 0) {
    float cc = 0.f;
    for (int j = 0; j < DMODEL; ++j) cc += W_le[d * DMODEL + j] * b_e2[j];
    cw[d] = cc;
  }
}

// ---------------------------------------------------------------------------
// edge kernel: ONE 64-edge tile per block; wave w owns output cols [64w,64w+64).
// B-fragments loaded from global per k-step (M/W_e1 are L2-resident; frees
// ~160 VGPRs vs register-persistent scheme -> 3 blocks/CU).
//   t1 = relu(raw @ W_e1^T + b_e1)    [K=64,  2 k-steps, 32 MFMA/wave]
//   pre = t1 @ M^T                    [K=256, 8 k-steps, 128 MFMA/wave]
//   msg = relu(x[src] + p'*(pre+c) + b_le); atomicAdd into aggr[dst]
// MFMA 16x16x32 bf16; C/D: col=lane&15, row=(lane>>4)*4+reg (+16*m).
// No tile loop: atomics drain at s_endpgm, not at a barrier.
// ---------------------------------------------------------------------------
__global__ __launch_bounds__(256, 3)
void edge_kernel(const float* __restrict__ x,
                 const int* __restrict__ eidx,
                 const float* __restrict__ eattr,
                 const ushort_t* __restrict__ We1bf,
                 const float* __restrict__ b_e1,
                 const float* __restrict__ b_le,
                 const ushort_t* __restrict__ Mw,
                 const float* __restrict__ cw,
                 float* __restrict__ aggr) {
  __shared__ __align__(16) ushort_t raw_lds[TILE_E * 72];   // 64x64 bf16 (+pad)
  __shared__ __align__(16) ushort_t t1_lds[TILE_E * 264];   // 64x256 bf16 (+pad)
  __shared__ float pp_lds[TILE_E];
  __shared__ int src_lds[TILE_E];
  __shared__ int dst_lds[TILE_E];

  const int tid  = threadIdx.x;
  const int lane = tid & 63;
  const int wave = tid >> 6;
  const int l16  = lane & 15;
  const int quad = lane >> 4;
  const long ebase = (long)blockIdx.x * TILE_E;

  int ncol[4];
  float be1v[4], cv[4], blv[4];
#pragma unroll
  for (int nt = 0; nt < 4; ++nt) {
    int n = wave * 64 + nt * 16 + l16;
    ncol[nt] = n;
    be1v[nt] = b_e1[n];
    cv[nt]   = cw[n];
    blv[nt]  = b_le[n];
  }

  // stage raw (edge_attr cols 1..64 as bf16), polarity, indices
  {
    int r0 = tid >> 4, c = (tid & 15) * 4;
#pragma unroll
    for (int p = 0; p < 4; ++p) {
      int r = p * 16 + r0;
      const float* sp = eattr + (ebase + r) * 65 + 1 + c;
      ushort_t* q = raw_lds + r * 72 + c;
      q[0] = f2bf(sp[0]); q[1] = f2bf(sp[1]); q[2] = f2bf(sp[2]); q[3] = f2bf(sp[3]);
    }
    if (tid < TILE_E) {
      float pol = eattr[(ebase + tid) * 65];
      pp_lds[tid] = fminf(fmaxf(pol, 0.f), 1.f) + 0.01f;
      src_lds[tid] = eidx[ebase + tid];
      dst_lds[tid] = eidx[N_EDGES + ebase + tid];
    }
  }
  __syncthreads();

  // GEMM1: t1 = relu(raw @ W_e1^T + b_e1)
  {
    floatx4 acc1[4][4];  // [m][nt]
#pragma unroll
    for (int m = 0; m < 4; ++m)
#pragma unroll
      for (int nt = 0; nt < 4; ++nt) acc1[m][nt] = (floatx4){0.f, 0.f, 0.f, 0.f};
#pragma unroll
    for (int k = 0; k < 2; ++k) {
      short8 a[4];
#pragma unroll
      for (int m = 0; m < 4; ++m)
        a[m] = *(const short8*)(const void*)(raw_lds + (m * 16 + l16) * 72 + k * 32 + quad * 8);
#pragma unroll
      for (int nt = 0; nt < 4; ++nt) {
        short8 b = ldg16(We1bf + ncol[nt] * FEDGE + k * 32 + quad * 8);
#pragma unroll
        for (int m = 0; m < 4; ++m)
          acc1[m][nt] = __builtin_amdgcn_mfma_f32_16x16x32_bf16(a[m], b, acc1[m][nt], 0, 0, 0);
      }
    }
#pragma unroll
    for (int m = 0; m < 4; ++m)
#pragma unroll
      for (int nt = 0; nt < 4; ++nt)
#pragma unroll
        for (int r = 0; r < 4; ++r)
          t1_lds[(m * 16 + quad * 4 + r) * 264 + ncol[nt]] =
              f2bf(fmaxf(acc1[m][nt][r] + be1v[nt], 0.f));
  }
  __syncthreads();

  // GEMM2: pre = t1 @ M^T
  floatx4 acc2[4][4];
#pragma unroll
  for (int m = 0; m < 4; ++m)
#pragma unroll
    for (int nt = 0; nt < 4; ++nt) acc2[m][nt] = (floatx4){0.f, 0.f, 0.f, 0.f};
#pragma unroll
  for (int k = 0; k < 8; ++k) {
    short8 a[4];
#pragma unroll
    for (int m = 0; m < 4; ++m)
      a[m] = *(const short8*)(const void*)(t1_lds + (m * 16 + l16) * 264 + k * 32 + quad * 8);
#pragma unroll
    for (int nt = 0; nt < 4; ++nt) {
      short8 b = ldg16(Mw + ncol[nt] * DMODEL + k * 32 + quad * 8);
#pragma unroll
      for (int m = 0; m < 4; ++m)
        acc2[m][nt] = __builtin_amdgcn_mfma_f32_16x16x32_bf16(a[m], b, acc2[m][nt], 0, 0, 0);
    }
  }

  // epilogue: msg = relu(x[src] + p'*(pre+c) + b_le) -> atomic scatter-add
#pragma unroll
  for (int m = 0; m < 4; ++m) {
#pragma unroll
    for (int r = 0; r < 4; ++r) {
      int row = m * 16 + quad * 4 + r;
      float pp = pp_lds[row];
      long srow = (long)src_lds[row] * DMODEL;
      long drow = (long)dst_lds[row] * DMODEL;
#pragma unroll
      for (int nt = 0; nt < 4; ++nt) {
        float emb = pp * (acc2[m][nt][r] + cv[nt]) + blv[nt];
        float msg = fmaxf(x[srow + ncol[nt]] + emb, 0.f);
        atomicAdd(aggr + drow + ncol[nt], msg);
      }
    }
  }
}

// ---------------------------------------------------------------------------
// node kernel: ONE 64-node tile per block.
//   h = (x+aggr) @ W_g1^T + b_g1 ; LayerNorm ; relu ; @ W_g2^T + b_g2
// h stays in registers; LN stats via per-lane nt-sum + shfl_xor over l16 +
// small LDS cross-wave combine. Last block (rows >= N_NODES) clamps loads,
// predicates stores.
// ---------------------------------------------------------------------------
__global__ __launch_bounds__(256, 3)
void node_kernel(const float* __restrict__ x,
                 const float* __restrict__ aggr,
                 const ushort_t* __restrict__ Wg1bf,
                 const float* __restrict__ b_g1,
                 const float* __restrict__ ln_g,
                 const float* __restrict__ ln_b,
                 const ushort_t* __restrict__ Wg2bf,
                 const float* __restrict__ b_g2,
                 float* __restrict__ out) {
  __shared__ __align__(16) ushort_t a_lds[TILE_N * 264];   // in / normalized (bf16)
  __shared__ float ws_s[4][TILE_N];    // per-wave row partial sums
  __shared__ float ws_ss[4][TILE_N];
  __shared__ float mu_lds[TILE_N], rs_lds[TILE_N];

  const int tid  = threadIdx.x;
  const int lane = tid & 63;
  const int wave = tid >> 6;
  const int l16  = lane & 15;
  const int quad = lane >> 4;
  const long nbase = (long)blockIdx.x * TILE_N;

  int ncol[4];
  float bg1[4], bg2[4], lgv[4], lbv[4];
#pragma unroll
  for (int nt = 0; nt < 4; ++nt) {
    int n = wave * 64 + nt * 16 + l16;
    ncol[nt] = n;
    bg1[nt] = b_g1[n]; bg2[nt] = b_g2[n];
    lgv[nt] = ln_g[n]; lbv[nt] = ln_b[n];
  }

  // stage in = bf16(x + aggr), rows clamped for the partial last block
  {
    int r0 = tid >> 4, c = (tid & 15) * 16;
#pragma unroll
    for (int p = 0; p < 4; ++p) {
      int r = p * 16 + r0;
      long rr = nbase + r; if (rr >= N_NODES) rr = N_NODES - 1;
      const float* xp = x + rr * DMODEL + c;
      const float* ap = aggr + rr * DMODEL + c;
      ushort_t* q = a_lds + r * 264 + c;
#pragma unroll
      for (int i = 0; i < 16; ++i) q[i] = f2bf(xp[i] + ap[i]);
    }
  }
  __syncthreads();

  // GEMM1: h = in @ W_g1^T + b_g1   (h stays in registers)
  floatx4 acc[4][4];
#pragma unroll
  for (int m = 0; m < 4; ++m)
#pragma unroll
    for (int nt = 0; nt < 4; ++nt) acc[m][nt] = (floatx4){0.f, 0.f, 0.f, 0.f};
#pragma unroll
  for (int k = 0; k < 8; ++k) {
    short8 a[4];
#pragma unroll
    for (int m = 0; m < 4; ++m)
      a[m] = *(const short8*)(const void*)(a_lds + (m * 16 + l16) * 264 + k * 32 + quad * 8);
#pragma unroll
    for (int nt = 0; nt < 4; ++nt) {
      short8 b = ldg16(Wg1bf + ncol[nt] * DMODEL + k * 32 + quad * 8);
#pragma unroll
      for (int m = 0; m < 4; ++m)
        acc[m][nt] = __builtin_amdgcn_mfma_f32_16x16x32_bf16(a[m], b, acc[m][nt], 0, 0, 0);
    }
  }
#pragma unroll
  for (int m = 0; m < 4; ++m)
#pragma unroll
    for (int nt = 0; nt < 4; ++nt)
#pragma unroll
      for (int r = 0; r < 4; ++r) acc[m][nt][r] += bg1[nt];

  // LN stats: per-lane sum over nt, shfl_xor reduce over l16, LDS combine
#pragma unroll
  for (int m = 0; m < 4; ++m) {
#pragma unroll
    for (int r = 0; r < 4; ++r) {
      float s = 0.f, ss = 0.f;
#pragma unroll
      for (int nt = 0; nt < 4; ++nt) { float v = acc[m][nt][r]; s += v; ss += v * v; }
#pragma unroll
      for (int o = 1; o <= 8; o <<= 1) { s += __shfl_xor(s, o); ss += __shfl_xor(ss, o); }
      if (l16 == 0) {
        int row = m * 16 + quad * 4 + r;
        ws_s[wave][row] = s; ws_ss[wave][row] = ss;
      }
    }
  }
  __syncthreads();
  if (tid < TILE_N) {
    float s = ws_s[0][tid] + ws_s[1][tid] + ws_s[2][tid] + ws_s[3][tid];
    float ss = ws_ss[0][tid] + ws_ss[1][tid] + ws_ss[2][tid] + ws_ss[3][tid];
    float mu = s * (1.f / 256.f);
    float var = ss * (1.f / 256.f) - mu * mu;
    mu_lds[tid] = mu;
    rs_lds[tid] = rsqrtf(var + 1e-5f);
  }
  __syncthreads();

  // normalize + relu -> a_lds (bf16); input tile is dead after GEMM1
#pragma unroll
  for (int m = 0; m < 4; ++m) {
#pragma unroll
    for (int r = 0; r < 4; ++r) {
      int row = m * 16 + quad * 4 + r;
      float mu = mu_lds[row], rs = rs_lds[row];
#pragma unroll
      for (int nt = 0; nt < 4; ++nt) {
        float hn = (acc[m][nt][r] - mu) * rs * lgv[nt] + lbv[nt];
        a_lds[row * 264 + ncol[nt]] = f2bf(fmaxf(hn, 0.f));
      }
    }
  }
  __syncthreads();

  // GEMM2 -> out
#pragma unroll
  for (int m = 0; m < 4; ++m)
#pragma unroll
    for (int nt = 0; nt < 4; ++nt) acc[m][nt] = (floatx4){0.f, 0.f, 0.f, 0.f};
#pragma unroll
  for (int k = 0; k < 8; ++k) {
    short8 a[4];
#pragma unroll
    for (int m = 0; m < 4; ++m)
      a[m] = *(const short8*)(const void*)(a_lds + (m * 16 + l16) * 264 + k * 32 + quad * 8);
#pragma unroll
    for (int nt = 0; nt < 4; ++nt) {
      short8 b = ldg16(Wg2bf + ncol[nt] * DMODEL + k * 32 + quad * 8);
#pragma unroll
      for (int m = 0; m < 4; ++m)
        acc[m][nt] = __builtin_amdgcn_mfma_f32_16x16x32_bf16(a[m], b, acc[m][nt], 0, 0, 0);
    }
  }
#pragma unroll
  for (int m = 0; m < 4; ++m) {
#pragma unroll
    for (int r = 0; r < 4; ++r) {
      long row = nbase + m * 16 + quad * 4 + r;
      if (row < N_NODES) {
#pragma unroll
        for (int nt = 0; nt < 4; ++nt)
          out[row * DMODEL + ncol[nt]] = acc[m][nt][r] + bg2[nt];
      }
    }
  }
}

// ---------------------------------------------------------------------------
extern "C" void kernel_launch(void* const* d_in, const int* in_sizes, int n_in,
                              void* d_out, int out_size, void* d_ws, size_t ws_size,
                              hipStream_t stream) {
  const float* x     = (const float*)d_in[0];
  const int*   eidx  = (const int*)d_in[1];
  const float* eattr = (const float*)d_in[2];
  const float* W_e1  = (const float*)d_in[3];
  const float* b_e1  = (const float*)d_in[4];
  const float* W_e2  = (const float*)d_in[5];
  const float* b_e2  = (const float*)d_in[6];
  const float* W_le  = (const float*)d_in[7];
  const float* b_le  = (const float*)d_in[8];
  const float* W_g1  = (const float*)d_in[9];
  const float* b_g1  = (const float*)d_in[10];
  const float* ln_g  = (const float*)d_in[11];
  const float* ln_b  = (const float*)d_in[12];
  const float* W_g2  = (const float*)d_in[13];
  const float* b_g2  = (const float*)d_in[14];
  float* out = (float*)d_out;

  char* ws = (char*)d_ws;
  ushort_t* Mw    = (ushort_t*)(ws);            // 131072 B
  ushort_t* Wg1bf = (ushort_t*)(ws + 131072);   // 131072 B
  ushort_t* Wg2bf = (ushort_t*)(ws + 262144);   // 131072 B
  ushort_t* We1bf = (ushort_t*)(ws + 393216);   // 32768 B
  float*    cw    = (float*)   (ws + 425984);   // 1024 B
  float*    aggr  = (float*)   (ws + 427008);   // 51.2 MB

  hipMemsetAsync(aggr, 0, (size_t)N_NODES * DMODEL * sizeof(float), stream);
  prep_kernel<<<dim3(DMODEL), dim3(DMODEL), 0, stream>>>(
      W_le, W_e2, b_e2, W_e1, W_g1, W_g2, Mw, cw, We1bf, Wg1bf, Wg2bf);
  edge_kernel<<<dim3(N_ETILES), dim3(256), 0, stream>>>(
      x, eidx, eattr, We1bf, b_e1, b_le, Mw, cw, aggr);
  node_kernel<<<dim3(N_NTILES), dim3(256), 0, stream>>>(
      x, aggr, Wg1bf, b_g1, ln_g, ln_b, Wg2bf, b_g2, out);
}

// Round 5
// 972.665 us; speedup vs baseline: 1.3597x; 1.2594x over previous
//
#include <hip/hip_runtime.h>
#include <stdint.h>

#define N_NODES 50000
#define N_EDGES 800000
#define DMODEL  256
#define FEDGE   64
#define TILE_E  64
#define N_ETILES (N_EDGES / TILE_E)   // 12500
#define TILE_N  64
#define N_NTILES ((N_NODES + TILE_N - 1) / TILE_N)  // 782

typedef short short8 __attribute__((ext_vector_type(8)));
typedef float floatx4 __attribute__((ext_vector_type(4)));
typedef unsigned short ushort_t;
typedef unsigned short ushort4v __attribute__((ext_vector_type(4)));

__device__ __forceinline__ ushort_t f2bf(float f) {
  union { float f; unsigned int i; } v; v.f = f;
  unsigned int x = v.i;
  unsigned int r = x + 0x7fffu + ((x >> 16) & 1u);  // RNE
  return (ushort_t)(r >> 16);
}
__device__ __forceinline__ short8 ldg16(const ushort_t* p) {
  return *(const short8*)(const void*)p;
}
__device__ __forceinline__ floatx4 ldf4(const float* p) {
  return *(const floatx4*)(const void*)p;
}

// ---------------------------------------------------------------------------
// prep: M = bf16(W_le @ W_e2), c = W_le @ b_e2 (f32); bf16 copies of
// W_e1 / W_g1 / W_g2. Fusion valid since polarity gate is a per-edge scalar:
//   edge_emb = p' * (t1 @ M^T + c) + b_le,  p' = clip(pol,0,1)+0.01
// ---------------------------------------------------------------------------
__global__ void prep_kernel(const float* __restrict__ W_le,
                            const float* __restrict__ W_e2,
                            const float* __restrict__ b_e2,
                            const float* __restrict__ W_e1,
                            const float* __restrict__ W_g1,
                            const float* __restrict__ W_g2,
                            ushort_t* __restrict__ Mw, float* __restrict__ cw,
                            ushort_t* __restrict__ We1bf,
                            ushort_t* __restrict__ Wg1bf,
                            ushort_t* __restrict__ Wg2bf) {
  int d = blockIdx.x, k = threadIdx.x;
  float acc = 0.f;
  for (int j = 0; j < DMODEL; ++j)
    acc += W_le[d * DMODEL + j] * W_e2[j * DMODEL + k];
  Mw[d * DMODEL + k] = f2bf(acc);
  Wg1bf[d * DMODEL + k] = f2bf(W_g1[d * DMODEL + k]);
  Wg2bf[d * DMODEL + k] = f2bf(W_g2[d * DMODEL + k]);
  if (k < FEDGE) We1bf[d * FEDGE + k] = f2bf(W_e1[d * FEDGE + k]);
  if (k == 0) {
    float cc = 0.f;
    for (int j = 0; j < DMODEL; ++j) cc += W_le[d * DMODEL + j] * b_e2[j];
    cw[d] = cc;
  }
}

// ---------------------------------------------------------------------------
// counting sort by dst: histogram -> single-block scan -> scatter(perm)
// ---------------------------------------------------------------------------
__global__ void hist_kernel(const int* __restrict__ eidx, int* __restrict__ counts) {
  int e = blockIdx.x * blockDim.x + threadIdx.x;
  if (e < N_EDGES) atomicAdd(counts + eidx[N_EDGES + e], 1);
}

__global__ void scan_kernel(const int* __restrict__ counts, int* __restrict__ cur) {
  __shared__ int lds[1024];
  const int tid = threadIdx.x;
  int carry = 0;
  for (int base = 0; base < N_NODES; base += 1024) {
    int i = base + tid;
    int v = (i < N_NODES) ? counts[i] : 0;
    lds[tid] = v;
    __syncthreads();
#pragma unroll
    for (int off = 1; off < 1024; off <<= 1) {
      int t = (tid >= off) ? lds[tid - off] : 0;
      __syncthreads();
      lds[tid] += t;
      __syncthreads();
    }
    if (i < N_NODES) cur[i] = carry + lds[tid] - v;   // exclusive
    int tot = lds[1023];
    __syncthreads();
    carry += tot;
  }
}

__global__ void scatter_kernel(const int* __restrict__ eidx, int* __restrict__ cur,
                               int* __restrict__ perm) {
  int e = blockIdx.x * blockDim.x + threadIdx.x;
  if (e < N_EDGES) {
    int d = eidx[N_EDGES + e];
    int pos = atomicAdd(cur + d, 1);
    perm[pos] = e;
  }
}

// ---------------------------------------------------------------------------
// edge kernel (dst-sorted, transposed GEMMs): D[m=dcol][n=edge].
//   t1^T = relu(W_e1 raw^T + b)   [K=64]
//   pre^T = M t1^T                [K=256]
//   msg = relu(x[src] + p'*(pre+c) + b_le)
// Segment boundaries in the sorted dst sequence are wave-uniform; each wave
// stages msg (its 64 d x 32 e half) in LDS overlaying dead t1, reduces runs
// of equal dst, and atomically flushes ONE coalesced row-add per segment.
// Atomic dword traffic: 819MB -> ~64MB.
// ---------------------------------------------------------------------------
__global__ __launch_bounds__(256, 3)
void edge_kernel(const float* __restrict__ x,
                 const int* __restrict__ eidx,
                 const float* __restrict__ eattr,
                 const int* __restrict__ perm,
                 const ushort_t* __restrict__ We1bf,
                 const float* __restrict__ b_e1,
                 const float* __restrict__ b_le,
                 const ushort_t* __restrict__ Mw,
                 const float* __restrict__ cw,
                 float* __restrict__ aggr) {
  __shared__ __align__(16) ushort_t raw_lds[TILE_E * 72];   // 64x64 bf16 (+pad)
  __shared__ __align__(16) ushort_t t1_lds[TILE_E * 264];   // 64x256 bf16; reused as msg f32
  __shared__ float pp_lds[TILE_E];
  __shared__ int src_lds[TILE_E];
  __shared__ int dst_lds[TILE_E + 1];

  const int tid  = threadIdx.x;
  const int lane = tid & 63;
  const int wave = tid >> 6;
  const int l16  = lane & 15;
  const int quad = lane >> 4;
  const int dbase = wave * 64;
  const long ebase = (long)blockIdx.x * TILE_E;

  // stage raw (gathered via perm; edge_attr cols 1..64 as bf16), pol, src, dst
  {
    int r0 = tid >> 4, c = (tid & 15) * 4;
#pragma unroll
    for (int p = 0; p < 4; ++p) {
      int r = p * 16 + r0;
      int pe = perm[ebase + r];                    // uniform per 16-lane group
      const float* sp = eattr + (long)pe * 65 + 1 + c;
      ushort4v pk = {f2bf(sp[0]), f2bf(sp[1]), f2bf(sp[2]), f2bf(sp[3])};
      *(ushort4v*)(void*)(raw_lds + r * 72 + c) = pk;
    }
    if (tid < TILE_E) {
      int pe = perm[ebase + tid];
      float pol = eattr[(long)pe * 65];
      pp_lds[tid] = fminf(fmaxf(pol, 0.f), 1.f) + 0.01f;
      src_lds[tid] = eidx[pe];
      dst_lds[tid] = eidx[N_EDGES + pe];
    }
    if (tid == 64) dst_lds[TILE_E] = -1;           // force flush at tile end
  }
  __syncthreads();

  // GEMM1 (transposed): t1^T[f][e]
  {
    floatx4 acc1[4][4];
#pragma unroll
    for (int m = 0; m < 4; ++m)
#pragma unroll
      for (int j = 0; j < 4; ++j) acc1[m][j] = (floatx4){0.f, 0.f, 0.f, 0.f};
#pragma unroll
    for (int kt = 0; kt < 2; ++kt) {
      short8 aW[4], bE[4];
#pragma unroll
      for (int m = 0; m < 4; ++m)
        aW[m] = ldg16(We1bf + (dbase + m * 16 + l16) * FEDGE + kt * 32 + quad * 8);
#pragma unroll
      for (int j = 0; j < 4; ++j)
        bE[j] = *(const short8*)(const void*)(raw_lds + (j * 16 + l16) * 72 + kt * 32 + quad * 8);
#pragma unroll
      for (int m = 0; m < 4; ++m)
#pragma unroll
        for (int j = 0; j < 4; ++j)
          acc1[m][j] = __builtin_amdgcn_mfma_f32_16x16x32_bf16(aW[m], bE[j], acc1[m][j], 0, 0, 0);
    }
#pragma unroll
    for (int m = 0; m < 4; ++m) {
      int f0 = dbase + m * 16 + quad * 4;
      floatx4 be1q = ldf4(b_e1 + f0);
#pragma unroll
      for (int j = 0; j < 4; ++j) {
        int e = j * 16 + l16;
        ushort4v pk = {f2bf(fmaxf(acc1[m][j][0] + be1q[0], 0.f)),
                       f2bf(fmaxf(acc1[m][j][1] + be1q[1], 0.f)),
                       f2bf(fmaxf(acc1[m][j][2] + be1q[2], 0.f)),
                       f2bf(fmaxf(acc1[m][j][3] + be1q[3], 0.f))};
        *(ushort4v*)(void*)(t1_lds + e * 264 + f0) = pk;
      }
    }
  }
  __syncthreads();

  // GEMM2 (transposed): pre^T[d][e]
  floatx4 acc2[4][4];
#pragma unroll
  for (int m = 0; m < 4; ++m)
#pragma unroll
    for (int j = 0; j < 4; ++j) acc2[m][j] = (floatx4){0.f, 0.f, 0.f, 0.f};
#pragma unroll
  for (int kt = 0; kt < 8; ++kt) {
    short8 aW[4], bE[4];
#pragma unroll
    for (int m = 0; m < 4; ++m)
      aW[m] = ldg16(Mw + (dbase + m * 16 + l16) * DMODEL + kt * 32 + quad * 8);
#pragma unroll
    for (int j = 0; j < 4; ++j)
      bE[j] = *(const short8*)(const void*)(t1_lds + (j * 16 + l16) * 264 + kt * 32 + quad * 8);
#pragma unroll
    for (int m = 0; m < 4; ++m)
#pragma unroll
      for (int j = 0; j < 4; ++j)
        acc2[m][j] = __builtin_amdgcn_mfma_f32_16x16x32_bf16(aW[m], bE[j], acc2[m][j], 0, 0, 0);
  }
  __syncthreads();   // t1 dead; LDS reused as per-wave msg buffer

  // msg + segmented reduction, two 32-edge halves
  floatx4 cv4[4], blv4[4];
#pragma unroll
  for (int m = 0; m < 4; ++m) {
    int d0 = dbase + m * 16 + quad * 4;
    cv4[m] = ldf4(cw + d0);
    blv4[m] = ldf4(b_le + d0);
  }
  float* msgw = ((float*)(void*)t1_lds) + wave * (64 * 33);  // [d_local][e_half], stride 33
  float runsum = 0.f;
  const int d_own = dbase + lane;

#pragma unroll
  for (int h = 0; h < 2; ++h) {
#pragma unroll
    for (int jj = 0; jj < 2; ++jj) {
      int j = h * 2 + jj;
      int e = j * 16 + l16;
      float pp = pp_lds[e];
      long srow = (long)src_lds[e] * DMODEL;
#pragma unroll
      for (int m = 0; m < 4; ++m) {
        int d0 = m * 16 + quad * 4;
        floatx4 xv = ldf4(x + srow + dbase + d0);
#pragma unroll
        for (int r = 0; r < 4; ++r)
          msgw[(d0 + r) * 33 + jj * 16 + l16] =
              fmaxf(xv[r] + pp * (acc2[m][j][r] + cv4[m][r]) + blv4[m][r], 0.f);
      }
    }
    __syncthreads();
    for (int el = 0; el < 32; ++el) {
      int eg = h * 32 + el;
      runsum += msgw[lane * 33 + el];
      if (dst_lds[eg] != dst_lds[eg + 1]) {
        atomicAdd(aggr + (long)dst_lds[eg] * DMODEL + d_own, runsum);
        runsum = 0.f;
      }
    }
    __syncthreads();
  }
}

// ---------------------------------------------------------------------------
// node kernel, TRANSPOSED: h^T[d][node] in registers; in-register LN with
// quad-shfl + cross-wave LDS combine; float4 out stores.
// ---------------------------------------------------------------------------
__global__ __launch_bounds__(256, 3)
void node_kernel(const float* __restrict__ x,
                 const float* __restrict__ aggr,
                 const ushort_t* __restrict__ Wg1bf,
                 const float* __restrict__ b_g1,
                 const float* __restrict__ ln_g,
                 const float* __restrict__ ln_b,
                 const ushort_t* __restrict__ Wg2bf,
                 const float* __restrict__ b_g2,
                 float* __restrict__ out) {
  __shared__ __align__(16) ushort_t a_lds[TILE_N * 264];
  __shared__ float ws_s[4][TILE_N];
  __shared__ float ws_ss[4][TILE_N];
  __shared__ float mu_lds[TILE_N], rs_lds[TILE_N];

  const int tid  = threadIdx.x;
  const int lane = tid & 63;
  const int wave = tid >> 6;
  const int l16  = lane & 15;
  const int quad = lane >> 4;
  const int dbase = wave * 64;
  const long nbase = (long)blockIdx.x * TILE_N;

#pragma unroll
  for (int i = 0; i < 16; ++i) {
    int id = tid + 256 * i;
    int r = id >> 6, c4 = (id & 63) * 4;
    long rr = nbase + r; if (rr >= N_NODES) rr = N_NODES - 1;
    floatx4 xv = ldf4(x + rr * DMODEL + c4);
    floatx4 av = ldf4(aggr + rr * DMODEL + c4);
    ushort4v pk = {f2bf(xv[0] + av[0]), f2bf(xv[1] + av[1]),
                   f2bf(xv[2] + av[2]), f2bf(xv[3] + av[3])};
    *(ushort4v*)(void*)(a_lds + r * 264 + c4) = pk;
  }
  __syncthreads();

  floatx4 acc[4][4];
#pragma unroll
  for (int m = 0; m < 4; ++m)
#pragma unroll
    for (int j = 0; j < 4; ++j) acc[m][j] = (floatx4){0.f, 0.f, 0.f, 0.f};
#pragma unroll
  for (int kt = 0; kt < 8; ++kt) {
    short8 aW[4], bN[4];
#pragma unroll
    for (int m = 0; m < 4; ++m)
      aW[m] = ldg16(Wg1bf + (dbase + m * 16 + l16) * DMODEL + kt * 32 + quad * 8);
#pragma unroll
    for (int j = 0; j < 4; ++j)
      bN[j] = *(const short8*)(const void*)(a_lds + (j * 16 + l16) * 264 + kt * 32 + quad * 8);
#pragma unroll
    for (int m = 0; m < 4; ++m)
#pragma unroll
      for (int j = 0; j < 4; ++j)
        acc[m][j] = __builtin_amdgcn_mfma_f32_16x16x32_bf16(aW[m], bN[j], acc[m][j], 0, 0, 0);
  }
#pragma unroll
  for (int m = 0; m < 4; ++m) {
    floatx4 bq = ldf4(b_g1 + dbase + m * 16 + quad * 4);
#pragma unroll
    for (int j = 0; j < 4; ++j)
#pragma unroll
      for (int r = 0; r < 4; ++r) acc[m][j][r] += bq[r];
  }

#pragma unroll
  for (int j = 0; j < 4; ++j) {
    float s = 0.f, ss = 0.f;
#pragma unroll
    for (int m = 0; m < 4; ++m)
#pragma unroll
      for (int r = 0; r < 4; ++r) { float v = acc[m][j][r]; s += v; ss += v * v; }
    s += __shfl_xor(s, 16); ss += __shfl_xor(ss, 16);
    s += __shfl_xor(s, 32); ss += __shfl_xor(ss, 32);
    if (quad == 0) { ws_s[wave][j * 16 + l16] = s; ws_ss[wave][j * 16 + l16] = ss; }
  }
  __syncthreads();
  if (tid < TILE_N) {
    float s = ws_s[0][tid] + ws_s[1][tid] + ws_s[2][tid] + ws_s[3][tid];
    float ss = ws_ss[0][tid] + ws_ss[1][tid] + ws_ss[2][tid] + ws_ss[3][tid];
    float mu = s * (1.f / 256.f);
    float var = ss * (1.f / 256.f) - mu * mu;
    mu_lds[tid] = mu;
    rs_lds[tid] = rsqrtf(var + 1e-5f);
  }
  __syncthreads();

#pragma unroll
  for (int m = 0; m < 4; ++m) {
    int d0 = dbase + m * 16 + quad * 4;
    floatx4 lg = ldf4(ln_g + d0), lb = ldf4(ln_b + d0);
#pragma unroll
    for (int j = 0; j < 4; ++j) {
      int e = j * 16 + l16;
      float mu = mu_lds[e], rs = rs_lds[e];
      ushort4v pk = {f2bf(fmaxf((acc[m][j][0] - mu) * rs * lg[0] + lb[0], 0.f)),
                     f2bf(fmaxf((acc[m][j][1] - mu) * rs * lg[1] + lb[1], 0.f)),
                     f2bf(fmaxf((acc[m][j][2] - mu) * rs * lg[2] + lb[2], 0.f)),
                     f2bf(fmaxf((acc[m][j][3] - mu) * rs * lg[3] + lb[3], 0.f))};
      *(ushort4v*)(void*)(a_lds + e * 264 + d0) = pk;
    }
  }
  __syncthreads();

#pragma unroll
  for (int m = 0; m < 4; ++m)
#pragma unroll
    for (int j = 0; j < 4; ++j) acc[m][j] = (floatx4){0.f, 0.f, 0.f, 0.f};
#pragma unroll
  for (int kt = 0; kt < 8; ++kt) {
    short8 aW[4], bN[4];
#pragma unroll
    for (int m = 0; m < 4; ++m)
      aW[m] = ldg16(Wg2bf + (dbase + m * 16 + l16) * DMODEL + kt * 32 + quad * 8);
#pragma unroll
    for (int j = 0; j < 4; ++j)
      bN[j] = *(const short8*)(const void*)(a_lds + (j * 16 + l16) * 264 + kt * 32 + quad * 8);
#pragma unroll
    for (int m = 0; m < 4; ++m)
#pragma unroll
      for (int j = 0; j < 4; ++j)
        acc[m][j] = __builtin_amdgcn_mfma_f32_16x16x32_bf16(aW[m], bN[j], acc[m][j], 0, 0, 0);
  }
#pragma unroll
  for (int m = 0; m < 4; ++m) {
    int d0 = dbase + m * 16 + quad * 4;
    floatx4 bq = ldf4(b_g2 + d0);
#pragma unroll
    for (int j = 0; j < 4; ++j) {
      long row = nbase + j * 16 + l16;
      if (row < N_NODES) {
        floatx4 o = {acc[m][j][0] + bq[0], acc[m][j][1] + bq[1],
                     acc[m][j][2] + bq[2], acc[m][j][3] + bq[3]};
        *(floatx4*)(void*)(out + row * DMODEL + d0) = o;
      }
    }
  }
}

// ---------------------------------------------------------------------------
extern "C" void kernel_launch(void* const* d_in, const int* in_sizes, int n_in,
                              void* d_out, int out_size, void* d_ws, size_t ws_size,
                              hipStream_t stream) {
  const float* x     = (const float*)d_in[0];
  const int*   eidx  = (const int*)d_in[1];
  const float* eattr = (const float*)d_in[2];
  const float* W_e1  = (const float*)d_in[3];
  const float* b_e1  = (const float*)d_in[4];
  const float* W_e2  = (const float*)d_in[5];
  const float* b_e2  = (const float*)d_in[6];
  const float* W_le  = (const float*)d_in[7];
  const float* b_le  = (const float*)d_in[8];
  const float* W_g1  = (const float*)d_in[9];
  const float* b_g1  = (const float*)d_in[10];
  const float* ln_g  = (const float*)d_in[11];
  const float* ln_b  = (const float*)d_in[12];
  const float* W_g2  = (const float*)d_in[13];
  const float* b_g2  = (const float*)d_in[14];
  float* out = (float*)d_out;

  char* ws = (char*)d_ws;
  ushort_t* Mw     = (ushort_t*)(ws);                 // 131072 B
  ushort_t* Wg1bf  = (ushort_t*)(ws + 131072);        // 131072 B
  ushort_t* Wg2bf  = (ushort_t*)(ws + 262144);        // 131072 B
  ushort_t* We1bf  = (ushort_t*)(ws + 393216);        // 32768 B
  float*    cw     = (float*)   (ws + 425984);        // 1024 B
  float*    aggr   = (float*)   (ws + 427008);        // 51,200,000 B
  int*      counts = (int*)     (ws + 51627008);      // 200,000 B
  int*      cur    = (int*)     (ws + 51827008);      // 200,000 B
  int*      perm   = (int*)     (ws + 52027008);      // 3,200,000 B -> 55,227,008 total

  hipMemsetAsync(aggr, 0, (size_t)N_NODES * DMODEL * sizeof(float), stream);
  hipMemsetAsync(counts, 0, (size_t)N_NODES * sizeof(int), stream);
  prep_kernel<<<dim3(DMODEL), dim3(DMODEL), 0, stream>>>(
      W_le, W_e2, b_e2, W_e1, W_g1, W_g2, Mw, cw, We1bf, Wg1bf, Wg2bf);
  hist_kernel<<<dim3((N_EDGES + 255) / 256), dim3(256), 0, stream>>>(eidx, counts);
  scan_kernel<<<dim3(1), dim3(1024), 0, stream>>>(counts, cur);
  scatter_kernel<<<dim3((N_EDGES + 255) / 256), dim3(256), 0, stream>>>(eidx, cur, perm);
  edge_kernel<<<dim3(N_ETILES), dim3(256), 0, stream>>>(
      x, eidx, eattr, perm, We1bf, b_e1, b_le, Mw, cw, aggr);
  node_kernel<<<dim3(N_NTILES), dim3(256), 0, stream>>>(
      x, aggr, Wg1bf, b_g1, ln_g, ln_b, Wg2bf, b_g2, out);
}

// Round 6
// 952.371 us; speedup vs baseline: 1.3887x; 1.0213x over previous
//
#include <hip/hip_runtime.h>
#include <stdint.h>

#define N_NODES 50000
#define N_EDGES 800000
#define DMODEL  256
#define FEDGE   64
#define TILE_E  64
#define N_ETILES (N_EDGES / TILE_E)   // 12500
#define TILE_N  64
#define N_NTILES ((N_NODES + TILE_N - 1) / TILE_N)  // 782
#define NB_SCAN ((N_NODES + 255) / 256)             // 196

typedef short short8 __attribute__((ext_vector_type(8)));
typedef float floatx4 __attribute__((ext_vector_type(4)));
typedef unsigned short ushort_t;
typedef unsigned short ushort4v __attribute__((ext_vector_type(4)));

__device__ __forceinline__ ushort_t f2bf(float f) {
  union { float f; unsigned int i; } v; v.f = f;
  unsigned int x = v.i;
  unsigned int r = x + 0x7fffu + ((x >> 16) & 1u);  // RNE
  return (ushort_t)(r >> 16);
}
__device__ __forceinline__ float bf2f(ushort_t u) {
  union { unsigned int i; float f; } v; v.i = ((unsigned int)u) << 16; return v.f;
}
__device__ __forceinline__ short8 ldg16(const ushort_t* p) {
  return *(const short8*)(const void*)p;
}
__device__ __forceinline__ floatx4 ldf4(const float* p) {
  return *(const floatx4*)(const void*)p;
}

// ---------------------------------------------------------------------------
// prep: M = bf16(W_le @ W_e2), c = W_le @ b_e2 (f32); bf16 copies of weights.
// Fusion valid since polarity gate is a per-edge scalar.
// ---------------------------------------------------------------------------
__global__ void prep_kernel(const float* __restrict__ W_le,
                            const float* __restrict__ W_e2,
                            const float* __restrict__ b_e2,
                            const float* __restrict__ W_e1,
                            const float* __restrict__ W_g1,
                            const float* __restrict__ W_g2,
                            ushort_t* __restrict__ Mw, float* __restrict__ cw,
                            ushort_t* __restrict__ We1bf,
                            ushort_t* __restrict__ Wg1bf,
                            ushort_t* __restrict__ Wg2bf) {
  int d = blockIdx.x, k = threadIdx.x;
  float acc = 0.f;
  for (int j = 0; j < DMODEL; ++j)
    acc += W_le[d * DMODEL + j] * W_e2[j * DMODEL + k];
  Mw[d * DMODEL + k] = f2bf(acc);
  Wg1bf[d * DMODEL + k] = f2bf(W_g1[d * DMODEL + k]);
  Wg2bf[d * DMODEL + k] = f2bf(W_g2[d * DMODEL + k]);
  if (k < FEDGE) We1bf[d * FEDGE + k] = f2bf(W_e1[d * FEDGE + k]);
  if (k == 0) {
    float cc = 0.f;
    for (int j = 0; j < DMODEL; ++j) cc += W_le[d * DMODEL + j] * b_e2[j];
    cw[d] = cc;
  }
}

// x -> bf16 copy (makes the edge gather 2B/elem and L3-resident: 25.6 MB)
__global__ void xconv_kernel(const float* __restrict__ x, ushort_t* __restrict__ xbf) {
  int i = blockIdx.x * blockDim.x + threadIdx.x;   // one float4 per thread
  floatx4 v = ldf4(x + (long)i * 4);
  ushort4v pk = {f2bf(v[0]), f2bf(v[1]), f2bf(v[2]), f2bf(v[3])};
  *(ushort4v*)(void*)(xbf + (long)i * 4) = pk;
}

// ---------------------------------------------------------------------------
// counting sort by dst: histogram -> 3-phase shfl scan -> scatter(perm)
// ---------------------------------------------------------------------------
__global__ void hist_kernel(const int* __restrict__ eidx, int* __restrict__ counts) {
  int e = blockIdx.x * blockDim.x + threadIdx.x;
  if (e < N_EDGES) atomicAdd(counts + eidx[N_EDGES + e], 1);
}

__global__ void scan_block_kernel(const int* __restrict__ counts,
                                  int* __restrict__ cur, int* __restrict__ bsum) {
  __shared__ int wsum[4];
  int i = blockIdx.x * 256 + threadIdx.x;
  int lane = threadIdx.x & 63, wave = threadIdx.x >> 6;
  int v = (i < N_NODES) ? counts[i] : 0;
  int s = v;
#pragma unroll
  for (int off = 1; off <= 32; off <<= 1) {
    int t = __shfl_up(s, off);
    if (lane >= off) s += t;
  }
  if (lane == 63) wsum[wave] = s;
  __syncthreads();
  int woff = 0;
  if (wave > 0) woff += wsum[0];
  if (wave > 1) woff += wsum[1];
  if (wave > 2) woff += wsum[2];
  if (i < N_NODES) cur[i] = s - v + woff;            // block-local exclusive
  if (threadIdx.x == 255) bsum[blockIdx.x] = s + woff;
}

__global__ void scan_total_kernel(const int* __restrict__ bsum, int* __restrict__ bofs) {
  __shared__ int wsum[4];
  int tid = threadIdx.x;
  int lane = tid & 63, wave = tid >> 6;
  int v = (tid < NB_SCAN) ? bsum[tid] : 0;
  int s = v;
#pragma unroll
  for (int off = 1; off <= 32; off <<= 1) {
    int t = __shfl_up(s, off);
    if (lane >= off) s += t;
  }
  if (lane == 63) wsum[wave] = s;
  __syncthreads();
  int woff = 0;
  if (wave > 0) woff += wsum[0];
  if (wave > 1) woff += wsum[1];
  if (wave > 2) woff += wsum[2];
  if (tid < NB_SCAN) bofs[tid] = s - v + woff;
}

__global__ void scan_add_kernel(int* __restrict__ cur, const int* __restrict__ bofs) {
  int i = blockIdx.x * 256 + threadIdx.x;
  if (i < N_NODES) cur[i] += bofs[i >> 8];
}

__global__ void scatter_kernel(const int* __restrict__ eidx, int* __restrict__ cur,
                               int* __restrict__ perm) {
  int e = blockIdx.x * blockDim.x + threadIdx.x;
  if (e < N_EDGES) {
    int d = eidx[N_EDGES + e];
    int pos = atomicAdd(cur + d, 1);
    perm[pos] = e;
  }
}

// ---------------------------------------------------------------------------
// edge kernel (dst-sorted, transposed GEMMs, x prefetched into registers).
// USEBF: gather x from bf16 copy (8B/lane frags) else f32 (16B/lane).
// ---------------------------------------------------------------------------
template <bool USEBF>
__global__ __launch_bounds__(256, 3)
void edge_kernel(const float* __restrict__ x,
                 const ushort_t* __restrict__ xbf,
                 const int* __restrict__ eidx,
                 const float* __restrict__ eattr,
                 const int* __restrict__ perm,
                 const ushort_t* __restrict__ We1bf,
                 const float* __restrict__ b_e1,
                 const float* __restrict__ b_le,
                 const ushort_t* __restrict__ Mw,
                 const float* __restrict__ cw,
                 float* __restrict__ aggr) {
  __shared__ __align__(16) ushort_t raw_lds[TILE_E * 72];
  __shared__ __align__(16) ushort_t t1_lds[TILE_E * 264];  // reused as msg f32
  __shared__ float pp_lds[TILE_E];
  __shared__ int src_lds[TILE_E];
  __shared__ int dst_lds[TILE_E + 1];

  const int tid  = threadIdx.x;
  const int lane = tid & 63;
  const int wave = tid >> 6;
  const int l16  = lane & 15;
  const int quad = lane >> 4;
  const int dbase = wave * 64;
  const long ebase = (long)blockIdx.x * TILE_E;

  // stage raw (gathered via perm), polarity, src, dst
  {
    int r0 = tid >> 4, c = (tid & 15) * 4;
#pragma unroll
    for (int p = 0; p < 4; ++p) {
      int r = p * 16 + r0;
      int pe = perm[ebase + r];
      const float* sp = eattr + (long)pe * 65 + 1 + c;
      ushort4v pk = {f2bf(sp[0]), f2bf(sp[1]), f2bf(sp[2]), f2bf(sp[3])};
      *(ushort4v*)(void*)(raw_lds + r * 72 + c) = pk;
    }
    if (tid < TILE_E) {
      int pe = perm[ebase + tid];
      float pol = eattr[(long)pe * 65];
      pp_lds[tid] = fminf(fmaxf(pol, 0.f), 1.f) + 0.01f;
      src_lds[tid] = eidx[pe];
      dst_lds[tid] = eidx[N_EDGES + pe];
    }
    if (tid == 64) dst_lds[TILE_E] = -1;
  }
  __syncthreads();

  // PREFETCH x[src] fragments into registers (hidden behind GEMM1/GEMM2)
  ushort4v xpb[4][4];
  floatx4  xpf[4][4];
#pragma unroll
  for (int j = 0; j < 4; ++j) {
    long srow = (long)src_lds[j * 16 + l16] * DMODEL;
#pragma unroll
    for (int m = 0; m < 4; ++m) {
      int d0 = dbase + m * 16 + quad * 4;
      if constexpr (USEBF)
        xpb[j][m] = *(const ushort4v*)(const void*)(xbf + srow + d0);
      else
        xpf[j][m] = ldf4(x + srow + d0);
    }
  }

  // GEMM1 (transposed): t1^T[f][e]
  {
    floatx4 acc1[4][4];
#pragma unroll
    for (int m = 0; m < 4; ++m)
#pragma unroll
      for (int j = 0; j < 4; ++j) acc1[m][j] = (floatx4){0.f, 0.f, 0.f, 0.f};
#pragma unroll
    for (int kt = 0; kt < 2; ++kt) {
      short8 aW[4], bE[4];
#pragma unroll
      for (int m = 0; m < 4; ++m)
        aW[m] = ldg16(We1bf + (dbase + m * 16 + l16) * FEDGE + kt * 32 + quad * 8);
#pragma unroll
      for (int j = 0; j < 4; ++j)
        bE[j] = *(const short8*)(const void*)(raw_lds + (j * 16 + l16) * 72 + kt * 32 + quad * 8);
#pragma unroll
      for (int m = 0; m < 4; ++m)
#pragma unroll
        for (int j = 0; j < 4; ++j)
          acc1[m][j] = __builtin_amdgcn_mfma_f32_16x16x32_bf16(aW[m], bE[j], acc1[m][j], 0, 0, 0);
    }
#pragma unroll
    for (int m = 0; m < 4; ++m) {
      int f0 = dbase + m * 16 + quad * 4;
      floatx4 be1q = ldf4(b_e1 + f0);
#pragma unroll
      for (int j = 0; j < 4; ++j) {
        int e = j * 16 + l16;
        ushort4v pk = {f2bf(fmaxf(acc1[m][j][0] + be1q[0], 0.f)),
                       f2bf(fmaxf(acc1[m][j][1] + be1q[1], 0.f)),
                       f2bf(fmaxf(acc1[m][j][2] + be1q[2], 0.f)),
                       f2bf(fmaxf(acc1[m][j][3] + be1q[3], 0.f))};
        *(ushort4v*)(void*)(t1_lds + e * 264 + f0) = pk;
      }
    }
  }
  __syncthreads();

  // GEMM2 (transposed): pre^T[d][e]
  floatx4 acc2[4][4];
#pragma unroll
  for (int m = 0; m < 4; ++m)
#pragma unroll
    for (int j = 0; j < 4; ++j) acc2[m][j] = (floatx4){0.f, 0.f, 0.f, 0.f};
#pragma unroll
  for (int kt = 0; kt < 8; ++kt) {
    short8 aW[4], bE[4];
#pragma unroll
    for (int m = 0; m < 4; ++m)
      aW[m] = ldg16(Mw + (dbase + m * 16 + l16) * DMODEL + kt * 32 + quad * 8);
#pragma unroll
    for (int j = 0; j < 4; ++j)
      bE[j] = *(const short8*)(const void*)(t1_lds + (j * 16 + l16) * 264 + kt * 32 + quad * 8);
#pragma unroll
    for (int m = 0; m < 4; ++m)
#pragma unroll
      for (int j = 0; j < 4; ++j)
        acc2[m][j] = __builtin_amdgcn_mfma_f32_16x16x32_bf16(aW[m], bE[j], acc2[m][j], 0, 0, 0);
  }
  __syncthreads();   // t1 dead; LDS reused as per-wave msg buffer

  floatx4 cv4[4], blv4[4];
#pragma unroll
  for (int m = 0; m < 4; ++m) {
    int d0 = dbase + m * 16 + quad * 4;
    cv4[m] = ldf4(cw + d0);
    blv4[m] = ldf4(b_le + d0);
  }
  float* msgw = ((float*)(void*)t1_lds) + wave * (64 * 33);
  float runsum = 0.f;
  const int d_own = dbase + lane;

#pragma unroll
  for (int h = 0; h < 2; ++h) {
#pragma unroll
    for (int jj = 0; jj < 2; ++jj) {
      int j = h * 2 + jj;
      int e = j * 16 + l16;
      float pp = pp_lds[e];
#pragma unroll
      for (int m = 0; m < 4; ++m) {
        int d0 = m * 16 + quad * 4;
        float xr[4];
        if constexpr (USEBF) {
#pragma unroll
          for (int r = 0; r < 4; ++r) xr[r] = bf2f(xpb[j][m][r]);
        } else {
#pragma unroll
          for (int r = 0; r < 4; ++r) xr[r] = xpf[j][m][r];
        }
#pragma unroll
        for (int r = 0; r < 4; ++r)
          msgw[(d0 + r) * 33 + jj * 16 + l16] =
              fmaxf(xr[r] + pp * (acc2[m][j][r] + cv4[m][r]) + blv4[m][r], 0.f);
      }
    }
    __syncthreads();
    for (int el = 0; el < 32; ++el) {
      int eg = h * 32 + el;
      runsum += msgw[lane * 33 + el];
      if (dst_lds[eg] != dst_lds[eg + 1]) {
        atomicAdd(aggr + (long)dst_lds[eg] * DMODEL + d_own, runsum);
        runsum = 0.f;
      }
    }
    __syncthreads();
  }
}

// ---------------------------------------------------------------------------
// node kernel, transposed; float4 I/O; in-register LN.
// ---------------------------------------------------------------------------
__global__ __launch_bounds__(256, 3)
void node_kernel(const float* __restrict__ x,
                 const float* __restrict__ aggr,
                 const ushort_t* __restrict__ Wg1bf,
                 const float* __restrict__ b_g1,
                 const float* __restrict__ ln_g,
                 const float* __restrict__ ln_b,
                 const ushort_t* __restrict__ Wg2bf,
                 const float* __restrict__ b_g2,
                 float* __restrict__ out) {
  __shared__ __align__(16) ushort_t a_lds[TILE_N * 264];
  __shared__ float ws_s[4][TILE_N];
  __shared__ float ws_ss[4][TILE_N];
  __shared__ float mu_lds[TILE_N], rs_lds[TILE_N];

  const int tid  = threadIdx.x;
  const int lane = tid & 63;
  const int wave = tid >> 6;
  const int l16  = lane & 15;
  const int quad = lane >> 4;
  const int dbase = wave * 64;
  const long nbase = (long)blockIdx.x * TILE_N;

#pragma unroll
  for (int i = 0; i < 16; ++i) {
    int id = tid + 256 * i;
    int r = id >> 6, c4 = (id & 63) * 4;
    long rr = nbase + r; if (rr >= N_NODES) rr = N_NODES - 1;
    floatx4 xv = ldf4(x + rr * DMODEL + c4);
    floatx4 av = ldf4(aggr + rr * DMODEL + c4);
    ushort4v pk = {f2bf(xv[0] + av[0]), f2bf(xv[1] + av[1]),
                   f2bf(xv[2] + av[2]), f2bf(xv[3] + av[3])};
    *(ushort4v*)(void*)(a_lds + r * 264 + c4) = pk;
  }
  __syncthreads();

  floatx4 acc[4][4];
#pragma unroll
  for (int m = 0; m < 4; ++m)
#pragma unroll
    for (int j = 0; j < 4; ++j) acc[m][j] = (floatx4){0.f, 0.f, 0.f, 0.f};
#pragma unroll
  for (int kt = 0; kt < 8; ++kt) {
    short8 aW[4], bN[4];
#pragma unroll
    for (int m = 0; m < 4; ++m)
      aW[m] = ldg16(Wg1bf + (dbase + m * 16 + l16) * DMODEL + kt * 32 + quad * 8);
#pragma unroll
    for (int j = 0; j < 4; ++j)
      bN[j] = *(const short8*)(const void*)(a_lds + (j * 16 + l16) * 264 + kt * 32 + quad * 8);
#pragma unroll
    for (int m = 0; m < 4; ++m)
#pragma unroll
      for (int j = 0; j < 4; ++j)
        acc[m][j] = __builtin_amdgcn_mfma_f32_16x16x32_bf16(aW[m], bN[j], acc[m][j], 0, 0, 0);
  }
#pragma unroll
  for (int m = 0; m < 4; ++m) {
    floatx4 bq = ldf4(b_g1 + dbase + m * 16 + quad * 4);
#pragma unroll
    for (int j = 0; j < 4; ++j)
#pragma unroll
      for (int r = 0; r < 4; ++r) acc[m][j][r] += bq[r];
  }

#pragma unroll
  for (int j = 0; j < 4; ++j) {
    float s = 0.f, ss = 0.f;
#pragma unroll
    for (int m = 0; m < 4; ++m)
#pragma unroll
      for (int r = 0; r < 4; ++r) { float v = acc[m][j][r]; s += v; ss += v * v; }
    s += __shfl_xor(s, 16); ss += __shfl_xor(ss, 16);
    s += __shfl_xor(s, 32); ss += __shfl_xor(ss, 32);
    if (quad == 0) { ws_s[wave][j * 16 + l16] = s; ws_ss[wave][j * 16 + l16] = ss; }
  }
  __syncthreads();
  if (tid < TILE_N) {
    float s = ws_s[0][tid] + ws_s[1][tid] + ws_s[2][tid] + ws_s[3][tid];
    float ss = ws_ss[0][tid] + ws_ss[1][tid] + ws_ss[2][tid] + ws_ss[3][tid];
    float mu = s * (1.f / 256.f);
    float var = ss * (1.f / 256.f) - mu * mu;
    mu_lds[tid] = mu;
    rs_lds[tid] = rsqrtf(var + 1e-5f);
  }
  __syncthreads();

#pragma unroll
  for (int m = 0; m < 4; ++m) {
    int d0 = dbase + m * 16 + quad * 4;
    floatx4 lg = ldf4(ln_g + d0), lb = ldf4(ln_b + d0);
#pragma unroll
    for (int j = 0; j < 4; ++j) {
      int e = j * 16 + l16;
      float mu = mu_lds[e], rs = rs_lds[e];
      ushort4v pk = {f2bf(fmaxf((acc[m][j][0] - mu) * rs * lg[0] + lb[0], 0.f)),
                     f2bf(fmaxf((acc[m][j][1] - mu) * rs * lg[1] + lb[1], 0.f)),
                     f2bf(fmaxf((acc[m][j][2] - mu) * rs * lg[2] + lb[2], 0.f)),
                     f2bf(fmaxf((acc[m][j][3] - mu) * rs * lg[3] + lb[3], 0.f))};
      *(ushort4v*)(void*)(a_lds + e * 264 + d0) = pk;
    }
  }
  __syncthreads();

#pragma unroll
  for (int m = 0; m < 4; ++m)
#pragma unroll
    for (int j = 0; j < 4; ++j) acc[m][j] = (floatx4){0.f, 0.f, 0.f, 0.f};
#pragma unroll
  for (int kt = 0; kt < 8; ++kt) {
    short8 aW[4], bN[4];
#pragma unroll
    for (int m = 0; m < 4; ++m)
      aW[m] = ldg16(Wg2bf + (dbase + m * 16 + l16) * DMODEL + kt * 32 + quad * 8);
#pragma unroll
    for (int j = 0; j < 4; ++j)
      bN[j] = *(const short8*)(const void*)(a_lds + (j * 16 + l16) * 264 + kt * 32 + quad * 8);
#pragma unroll
    for (int m = 0; m < 4; ++m)
#pragma unroll
      for (int j = 0; j < 4; ++j)
        acc[m][j] = __builtin_amdgcn_mfma_f32_16x16x32_bf16(aW[m], bN[j], acc[m][j], 0, 0, 0);
  }
#pragma unroll
  for (int m = 0; m < 4; ++m) {
    int d0 = dbase + m * 16 + quad * 4;
    floatx4 bq = ldf4(b_g2 + d0);
#pragma unroll
    for (int j = 0; j < 4; ++j) {
      long row = nbase + j * 16 + l16;
      if (row < N_NODES) {
        floatx4 o = {acc[m][j][0] + bq[0], acc[m][j][1] + bq[1],
                     acc[m][j][2] + bq[2], acc[m][j][3] + bq[3]};
        *(floatx4*)(void*)(out + row * DMODEL + d0) = o;
      }
    }
  }
}

// ---------------------------------------------------------------------------
extern "C" void kernel_launch(void* const* d_in, const int* in_sizes, int n_in,
                              void* d_out, int out_size, void* d_ws, size_t ws_size,
                              hipStream_t stream) {
  const float* x     = (const float*)d_in[0];
  const int*   eidx  = (const int*)d_in[1];
  const float* eattr = (const float*)d_in[2];
  const float* W_e1  = (const float*)d_in[3];
  const float* b_e1  = (const float*)d_in[4];
  const float* W_e2  = (const float*)d_in[5];
  const float* b_e2  = (const float*)d_in[6];
  const float* W_le  = (const float*)d_in[7];
  const float* b_le  = (const float*)d_in[8];
  const float* W_g1  = (const float*)d_in[9];
  const float* b_g1  = (const float*)d_in[10];
  const float* ln_g  = (const float*)d_in[11];
  const float* ln_b  = (const float*)d_in[12];
  const float* W_g2  = (const float*)d_in[13];
  const float* b_g2  = (const float*)d_in[14];
  float* out = (float*)d_out;

  char* ws = (char*)d_ws;
  ushort_t* Mw     = (ushort_t*)(ws);                 // 131072
  ushort_t* Wg1bf  = (ushort_t*)(ws + 131072);        // 131072
  ushort_t* Wg2bf  = (ushort_t*)(ws + 262144);        // 131072
  ushort_t* We1bf  = (ushort_t*)(ws + 393216);        // 32768
  float*    cw     = (float*)   (ws + 425984);        // 1024
  float*    aggr   = (float*)   (ws + 427008);        // 51,200,000
  int*      counts = (int*)     (ws + 51627008);      // 200,000
  int*      cur    = (int*)     (ws + 51827008);      // 200,000
  int*      perm   = (int*)     (ws + 52027008);      // 3,200,000
  int*      bsum   = (int*)     (ws + 55227008);      // 1,024
  int*      bofs   = (int*)     (ws + 55228032);      // 1,024
  ushort_t* xbf    = (ushort_t*)(ws + 55229056);      // 25,600,000 -> 80,829,056
  const size_t NEED_BF = 80829056;
  const bool use_bf = (ws_size >= NEED_BF);

  hipMemsetAsync(aggr, 0, (size_t)N_NODES * DMODEL * sizeof(float), stream);
  hipMemsetAsync(counts, 0, (size_t)N_NODES * sizeof(int), stream);
  prep_kernel<<<dim3(DMODEL), dim3(DMODEL), 0, stream>>>(
      W_le, W_e2, b_e2, W_e1, W_g1, W_g2, Mw, cw, We1bf, Wg1bf, Wg2bf);
  if (use_bf)
    xconv_kernel<<<dim3(N_NODES * DMODEL / 4 / 256), dim3(256), 0, stream>>>(x, xbf);
  hist_kernel<<<dim3((N_EDGES + 255) / 256), dim3(256), 0, stream>>>(eidx, counts);
  scan_block_kernel<<<dim3(NB_SCAN), dim3(256), 0, stream>>>(counts, cur, bsum);
  scan_total_kernel<<<dim3(1), dim3(256), 0, stream>>>(bsum, bofs);
  scan_add_kernel<<<dim3(NB_SCAN), dim3(256), 0, stream>>>(cur, bofs);
  scatter_kernel<<<dim3((N_EDGES + 255) / 256), dim3(256), 0, stream>>>(eidx, cur, perm);
  if (use_bf)
    edge_kernel<true><<<dim3(N_ETILES), dim3(256), 0, stream>>>(
        x, xbf, eidx, eattr, perm, We1bf, b_e1, b_le, Mw, cw, aggr);
  else
    edge_kernel<false><<<dim3(N_ETILES), dim3(256), 0, stream>>>(
        x, xbf, eidx, eattr, perm, We1bf, b_e1, b_le, Mw, cw, aggr);
  node_kernel<<<dim3(N_NTILES), dim3(256), 0, stream>>>(
      x, aggr, Wg1bf, b_g1, ln_g, ln_b, Wg2bf, b_g2, out);
}